// Round 26
// baseline (52.817 us; speedup 1.0000x reference)
//
#include <hip/hip_runtime.h>
#include <hip/hip_bf16.h>

constexpr int BB = 4;
constexpr int SS = 1024;
constexpr int HH = 16;
constexpr int DH = 64;
constexpr int DM = 1024;

using f32x16 = __attribute__((ext_vector_type(16))) float;
using s16x8  = __attribute__((ext_vector_type(8))) short;

__device__ __forceinline__ f32x16 mfma32(s16x8 a, s16x8 b, f32x16 c) {
    return __builtin_amdgcn_mfma_f32_32x32x16_bf16(a, b, c, 0, 0, 0);
}

__device__ __forceinline__ unsigned short bf16bits(float x) {
    union { __hip_bfloat16 h; unsigned short s; } cv;
    cv.h = __float2bfloat16(x);
    return cv.s;
}
__device__ __forceinline__ unsigned pk_bf16(float lo, float hi) {
    return (unsigned)bf16bits(lo) | ((unsigned)bf16bits(hi) << 16);
}

__device__ __forceinline__ float fast_exp2(float x) {
#if __has_builtin(__builtin_amdgcn_exp2f)
    return __builtin_amdgcn_exp2f(x);
#else
    return __expf(x * 0.6931471805599453f);
#endif
}

// pi permutation within a 32-key group (involution): swap 4-7<->8-11, 20-23<->24-27.
__device__ __forceinline__ int kperm(int g) {
    const int m = g & 12;
    return (m == 4 || m == 8) ? (g ^ 12) : g;
}

// ---------------- W pre-pack: fp32 -> bf16 B-fragments, ONCE (r24 validated) ----------------
__global__ __launch_bounds__(256) void w_pack_kernel(
    const float* __restrict__ Wq, const float* __restrict__ Wk, const float* __restrict__ Wv,
    __hip_bfloat16* __restrict__ wfrag)
{
    const int gid = blockIdx.x * 256 + threadIdx.x;   // 0..3071 = h*192 + m*64 + e
    const int e = gid & 63;
    const int m = (gid >> 6) % 3;
    const int h = gid / 192;
    const float* Wm = (m == 0) ? Wq : (m == 1) ? Wk : Wv;
    const float* src = Wm + (size_t)(h * DH + e) * DH;
    s16x8* dst = reinterpret_cast<s16x8*>(wfrag);
    #pragma unroll
    for (int s = 0; s < 4; ++s) {
        #pragma unroll
        for (int hi = 0; hi < 2; ++hi) {
            const float* p = src + s * 16 + hi * 8;
            float4 a  = reinterpret_cast<const float4*>(p)[0];
            float4 b4 = reinterpret_cast<const float4*>(p)[1];
            union { unsigned u[4]; s16x8 v; } f;
            f.u[0] = pk_bf16(a.x, a.y);   f.u[1] = pk_bf16(a.z, a.w);
            f.u[2] = pk_bf16(b4.x, b4.y); f.u[3] = pk_bf16(b4.z, b4.w);
            dst[(((h * 3 + m) * 4 + s) * 2 + hi) * 64 + e] = f.v;
        }
    }
}

// ---------------- QKV projection (MFMA, pre-packed W; V drained to FRAGMENT layout) ----------------
// Q/K drains as r24 ([pair][s][d] row-major). V drain = r21's VALIDATED vfrag layout:
//   vfrag[pair][g 32][half 2][s5 2][hi 2][dl 32]x8 : elem j = V[key=g*32+s5*16+hi*8+j][d=half*32+dl]
// so attention reads V as 1KB-contiguous per-wave fragments directly from global (L2-resident).
__global__ __launch_bounds__(256) void qkv_proj_kernel(
    const float* __restrict__ x,
    const __hip_bfloat16* __restrict__ wfrag,
    const float* __restrict__ bq, const float* __restrict__ bk, const float* __restrict__ bv,
    __hip_bfloat16* __restrict__ q_ws, __hip_bfloat16* __restrict__ k_ws,
    __hip_bfloat16* __restrict__ v_ws)
{
    const int bid  = blockIdx.x;
    const int tile = bid & 7;
    const int pair = bid >> 3;
    const int b = pair >> 4, h = pair & 15;
    const int t = threadIdx.x;
    const int w = t >> 6, l = t & 63;
    const int lq = l & 31, hi = l >> 5;
    const int s0 = tile * 128;

    __shared__ __align__(16) char Xs[16384];   // X stage [128 s][128B], then Q out
    __shared__ __align__(16) char Kt[16384];   // K out  [128 s][128B]
    __shared__ __align__(16) char Vt[16384];   // V out transposed [64 e][256B]

    {
        const float* xb = x + (size_t)(b * SS + s0) * DM + h * DH;
        #pragma unroll
        for (int i = 0; i < 8; ++i) {
            const int c  = t + 256 * i;
            const int r  = c >> 4, cw = c & 15;
            float4 v4 = *reinterpret_cast<const float4*>(xb + (size_t)r * DM + cw * 4);
            uint2 p;
            p.x = pk_bf16(v4.x, v4.y);
            p.y = pk_bf16(v4.z, v4.w);
            *reinterpret_cast<uint2*>(Xs + r * 128 + ((cw * 8) ^ ((r & 7) << 4))) = p;
        }
    }
    __syncthreads();

    const int arow = w * 32 + lq;
    const int asw  = (arow & 7) << 4;
    s16x8 af[4];
    #pragma unroll
    for (int s = 0; s < 4; ++s)
        af[s] = *reinterpret_cast<const s16x8*>(Xs + arow * 128 + ((s * 32 + hi * 16) ^ asw));
    __syncthreads();   // Xs now free for reuse as Q-out tile

    const s16x8* wfp = reinterpret_cast<const s16x8*>(wfrag);

    #pragma unroll
    for (int m = 0; m < 3; ++m) {
        const float* bm = (m == 0) ? bq : (m == 1) ? bk : bv;

        f32x16 a0, a1;
        #pragma unroll
        for (int r = 0; r < 16; ++r) { a0[r] = 0.0f; a1[r] = 0.0f; }

        #pragma unroll
        for (int s = 0; s < 4; ++s) {
            const int wb = (((h * 3 + m) * 4 + s) * 2 + hi) * 64;
            s16x8 bf0 = wfp[wb + lq];        // B-frag col e = lq
            s16x8 bf1 = wfp[wb + 32 + lq];   // B-frag col e = 32+lq
            a0 = mfma32(af[s], bf0, a0);
            a1 = mfma32(af[s], bf1, a1);
        }

        const float bias0 = bm[h * DH + lq];
        const float bias1 = bm[h * DH + 32 + lq];

        if (m < 2) {
            char* T = (m == 0) ? Xs : Kt;
            #pragma unroll
            for (int r = 0; r < 16; ++r) {
                const int row = w * 32 + (r & 3) + 8 * (r >> 2) + 4 * hi;
                const int sw  = (row & 7) << 4;
                *reinterpret_cast<unsigned short*>(T + row * 128 + ((lq * 2) ^ sw)) =
                    bf16bits(a0[r] + bias0);
                *reinterpret_cast<unsigned short*>(T + row * 128 + (((32 + lq) * 2) ^ sw)) =
                    bf16bits(a1[r] + bias1);
            }
        } else {
            #pragma unroll
            for (int g = 0; g < 4; ++g) {
                const int off = w * 64 + g * 16 + hi * 8;
                uint2 p0, p1;
                p0.x = pk_bf16(a0[4*g+0] + bias0, a0[4*g+1] + bias0);
                p0.y = pk_bf16(a0[4*g+2] + bias0, a0[4*g+3] + bias0);
                p1.x = pk_bf16(a1[4*g+0] + bias1, a1[4*g+1] + bias1);
                p1.y = pk_bf16(a1[4*g+2] + bias1, a1[4*g+3] + bias1);
                *reinterpret_cast<uint2*>(Vt + lq * 256 + (off ^ ((lq & 7) << 4))) = p0;
                *reinterpret_cast<uint2*>(Vt + (32 + lq) * 256 + (off ^ (((32 + lq) & 7) << 4))) = p1;
            }
        }
    }
    __syncthreads();

    #pragma unroll
    for (int i = 0; i < 4; ++i) {
        const int c   = t + 256 * i;
        const int row = c >> 3, cc = c & 7;
        const int off = row * 128 + ((cc * 16) ^ ((row & 7) << 4));
        s16x8 qv = *reinterpret_cast<const s16x8*>(Xs + off);
        *reinterpret_cast<s16x8*>(q_ws + ((size_t)pair * SS + s0 + row) * DH + cc * 8) = qv;
        s16x8 kv = *reinterpret_cast<const s16x8*>(Kt + off);
        *reinterpret_cast<s16x8*>(k_ws + ((size_t)pair * SS + s0 + row) * DH + cc * 8) = kv;
    }
    // V drain to fragment layout (r21 VALIDATED code)
    {
        s16x8* vo = reinterpret_cast<s16x8*>(v_ws);
        #pragma unroll
        for (int i = 0; i < 4; ++i) {
            const int c    = t + 256 * i;          // 0..1023
            const int dl   = c & 31;
            const int kc   = (c >> 5) & 15;        // key-chunk of 8 within this 128-key tile
            const int half = c >> 9;               // 0..1
            const int d    = half * 32 + dl;
            const int off  = d * 256 + ((kc * 16) ^ ((d & 7) << 4));
            const int gv   = tile * 4 + (kc >> 2);
            const int fb   = (((pair * 32 + gv) * 2 + half) * 2 + ((kc >> 1) & 1)) * 2 + (kc & 1);
            s16x8 vv = *reinterpret_cast<const s16x8*>(Vt + off);
            vo[fb * 32 + dl] = vv;
        }
    }
}

// ---------------- Flash attention: K in LDS (r15), V GLOBAL-DIRECT via vfrag ----------------
// grid 512; block 512 = 8 waves = 4 q-groups x 2 KV-parities. K: single 16KB pi-permuted
// swizzled LDS buffer (r15 path, staging loads halved). V: per-tile 8x 1KB-contiguous
// fragment loads from L2-resident vfrag, issued BEFORE QK^T, consumed after softmax
// (m169: don't LDS-stage what L2 serves; latency hidden under QK^T+softmax compute).
// Static-max softmax; sc packed to bf16 immediately after exp2 (shortens live ranges).
__global__ __launch_bounds__(512, 4) void attn_kernel(
    const __hip_bfloat16* __restrict__ q_ws,
    const __hip_bfloat16* __restrict__ k_ws,
    const __hip_bfloat16* __restrict__ vfrag,
    float* __restrict__ out)
{
    const int bid  = blockIdx.x;
    const int lbid = (bid & 7) * 64 + (bid >> 3);   // XCD-aware swizzle (512 % 8 == 0)
    const int qt   = lbid & 7;
    const int pair = lbid >> 3;
    const int b = pair >> 4, h = pair & 15;
    const int t = threadIdx.x;
    const int w = t >> 6, l = t & 63;
    const int lq = l & 31, hi = l >> 5;
    const int qg = w & 3, p = w >> 2;

    // K [128 keys][128B] swz (row&7)<<4 at 0 (16KB). Merge reuses region; l at 32768+qg*256.
    __shared__ __align__(16) char smem[33792];

    const __hip_bfloat16* qp =
        q_ws + ((size_t)pair * SS + qt * 128 + qg * 32 + lq) * DH + hi * 8;
    s16x8 qf[4];
    #pragma unroll
    for (int s5 = 0; s5 < 4; ++s5)
        qf[s5] = *reinterpret_cast<const s16x8*>(qp + s5 * 16);

    const int u0 = t, u1 = t + 512;
    const __hip_bfloat16* kb = k_ws + (size_t)pair * SS * DH;
    const s16x8* vfp = reinterpret_cast<const s16x8*>(vfrag);

    const int r0g = (u0 >> 3) & 31, r0m = r0g & 12;
    const int pr0 = (u0 >> 3 & ~31) | ((r0m == 4 || r0m == 8) ? (r0g ^ 12) : r0g);
    const int kOff0 = pr0 * 128 + (((u0 & 7) ^ (pr0 & 7)) << 4);
    const int r1g = (u1 >> 3) & 31, r1m = r1g & 12;
    const int pr1 = (u1 >> 3 & ~31) | ((r1m == 4 || r1m == 8) ? (r1g ^ 12) : r1g);
    const int kOff1 = pr1 * 128 + (((u1 & 7) ^ (pr1 & 7)) << 4);

    // prologue: K super-tile 0 -> buf
    {
        s16x8 k0 = *reinterpret_cast<const s16x8*>(kb + u0 * 8);
        s16x8 k1 = *reinterpret_cast<const s16x8*>(kb + u1 * 8);
        *reinterpret_cast<s16x8*>(smem + kOff0) = k0;
        *reinterpret_cast<s16x8*>(smem + kOff1) = k1;
    }
    __syncthreads();

    f32x16 o0, o1, lacc;
    #pragma unroll
    for (int r = 0; r < 16; ++r) { o0[r] = 0.0f; o1[r] = 0.0f; lacc[r] = 0.0f; }
    const float cml = 0.18033688011112042f;  // log2(e)/8 : folds 1/sqrt(64) + exp2 domain

    const int kbase0 = (p * 64 + lq) * 128;
    const int kbase1 = kbase0 + 32 * 128;
    const int swzK = (lq & 7) << 4;

    for (int st = 0; st < 8; ++st) {
        s16x8 kr0, kr1;
        if (st < 7) {                              // T14: next K super-tile loads first
            kr0 = *reinterpret_cast<const s16x8*>(kb + (st + 1) * 8192 + u0 * 8);
            kr1 = *reinterpret_cast<const s16x8*>(kb + (st + 1) * 8192 + u1 * 8);
        }

        // V fragments for THIS tile (groups gA=st*4+2p, gB=gA+1), issued EARLY:
        // consumed after QK^T + softmax (~400+ cycles of cover; L2-resident).
        const size_t vbase = ((size_t)(pair * 32 + st * 4 + 2 * p) * 8) * 32 + lq;
        s16x8 va0 = vfp[vbase + (size_t)(0  + hi) * 32];   // gA half0 s5'=0
        s16x8 va1 = vfp[vbase + (size_t)(2  + hi) * 32];   // gA half0 s5'=1
        s16x8 va2 = vfp[vbase + (size_t)(4  + hi) * 32];   // gA half1 s5'=0
        s16x8 va3 = vfp[vbase + (size_t)(6  + hi) * 32];   // gA half1 s5'=1
        s16x8 vb0 = vfp[vbase + (size_t)(8  + hi) * 32];   // gB half0 s5'=0
        s16x8 vb1 = vfp[vbase + (size_t)(10 + hi) * 32];   // gB half0 s5'=1
        s16x8 vb2 = vfp[vbase + (size_t)(12 + hi) * 32];   // gB half1 s5'=0
        s16x8 vb3 = vfp[vbase + (size_t)(14 + hi) * 32];   // gB half1 s5'=1

        const char* Kp = smem;

        // QK^T (swapped): lane = query lq; regs = 32 pi-permuted keys of the parity half
        f32x16 sc0, sc1;
        #pragma unroll
        for (int r = 0; r < 16; ++r) { sc0[r] = 0.0f; sc1[r] = 0.0f; }
        #pragma unroll
        for (int s5 = 0; s5 < 4; ++s5) {
            const int co = (2 * s5 + hi) << 4;
            s16x8 ka = *reinterpret_cast<const s16x8*>(Kp + kbase0 + (co ^ swzK));
            sc0 = mfma32(ka, qf[s5], sc0);
        }
        #pragma unroll
        for (int s5 = 0; s5 < 4; ++s5) {
            const int co = (2 * s5 + hi) << 4;
            s16x8 ka = *reinterpret_cast<const s16x8*>(Kp + kbase1 + (co ^ swzK));
            sc1 = mfma32(ka, qf[s5], sc1);
        }

        // static-max softmax; pack P to bf16 A-frags IMMEDIATELY (sc dies early)
        #pragma unroll
        for (int r = 0; r < 16; ++r) {
            sc0[r] = fast_exp2(sc0[r] * cml);
            sc1[r] = fast_exp2(sc1[r] * cml);
            lacc[r] += sc0[r] + sc1[r];
        }
        union { unsigned u[4]; s16x8 v; } af0, af1, af2, af3;
        af0.u[0] = pk_bf16(sc0[0],  sc0[1]);  af0.u[1] = pk_bf16(sc0[2],  sc0[3]);
        af0.u[2] = pk_bf16(sc0[4],  sc0[5]);  af0.u[3] = pk_bf16(sc0[6],  sc0[7]);
        af1.u[0] = pk_bf16(sc0[8],  sc0[9]);  af1.u[1] = pk_bf16(sc0[10], sc0[11]);
        af1.u[2] = pk_bf16(sc0[12], sc0[13]); af1.u[3] = pk_bf16(sc0[14], sc0[15]);
        af2.u[0] = pk_bf16(sc1[0],  sc1[1]);  af2.u[1] = pk_bf16(sc1[2],  sc1[3]);
        af2.u[2] = pk_bf16(sc1[4],  sc1[5]);  af2.u[3] = pk_bf16(sc1[6],  sc1[7]);
        af3.u[0] = pk_bf16(sc1[8],  sc1[9]);  af3.u[1] = pk_bf16(sc1[10], sc1[11]);
        af3.u[2] = pk_bf16(sc1[12], sc1[13]); af3.u[3] = pk_bf16(sc1[14], sc1[15]);

        // PV: same key-slot pairing as r15 (s5<2 -> gA, s5>=2 -> gB; halves -> o0/o1)
        o0 = mfma32(af0.v, va0, o0);
        o1 = mfma32(af0.v, va2, o1);
        o0 = mfma32(af1.v, va1, o0);
        o1 = mfma32(af1.v, va3, o1);
        o0 = mfma32(af2.v, vb0, o0);
        o1 = mfma32(af2.v, vb2, o1);
        o0 = mfma32(af3.v, vb1, o0);
        o1 = mfma32(af3.v, vb3, o1);

        __syncthreads();                           // all waves done reading K buf
        if (st < 7) {
            *reinterpret_cast<s16x8*>(smem + kOff0) = kr0;
            *reinterpret_cast<s16x8*>(smem + kOff1) = kr1;
            __syncthreads();                       // buf ready
        }
    }

    // ONE final reduction: tree over 16 regs + cross-half shfl -> lsum (per query lq)
    float ts[16];
    #pragma unroll
    for (int r = 0; r < 16; ++r) ts[r] = lacc[r];
    #pragma unroll
    for (int s = 8; s >= 1; s >>= 1)
        #pragma unroll
        for (int r = 0; r < 8; ++r)
            if (r < s) ts[r] += ts[r + s];
    const float lsum = ts[0] + __shfl_xor(ts[0], 32);

    // max-free split-K merge: (qg, p=0) <- (qg, p=1)  [r15 validated]
    float* Obuf = reinterpret_cast<float*>(smem + qg * 8192);          // [32 q][64 d] f32
    float* mlb  = reinterpret_cast<float*>(smem + 32768 + qg * 256);   // l[32]
    if (p == 1) {
        #pragma unroll
        for (int r = 0; r < 16; ++r) {
            const int qr = (r & 3) + 8 * (r >> 2) + 4 * hi;
            Obuf[qr * 64 + lq]      = o0[r];
            Obuf[qr * 64 + 32 + lq] = o1[r];
        }
        mlb[lq] = lsum;
    }
    __syncthreads();
    if (p == 0) {
        const float inv = 1.0f / (lsum + mlb[lq]);   // per query lq
        #pragma unroll
        for (int r = 0; r < 16; ++r) {
            const int qr = (r & 3) + 8 * (r >> 2) + 4 * hi;
            const float invr = __shfl(inv, qr);      // remap to query qr
            float* op = out + ((size_t)b * SS + qt * 128 + qg * 32 + qr) * DM + h * DH + lq;
            op[0]  = (o0[r] + Obuf[qr * 64 + lq])      * invr;
            op[32] = (o1[r] + Obuf[qr * 64 + 32 + lq]) * invr;
        }
    }
}

extern "C" void kernel_launch(void* const* d_in, const int* in_sizes, int n_in,
                              void* d_out, int out_size, void* d_ws, size_t ws_size,
                              hipStream_t stream) {
    const float* x  = (const float*)d_in[0];
    const float* Wq = (const float*)d_in[1];
    const float* Wk = (const float*)d_in[2];
    const float* Wv = (const float*)d_in[3];
    const float* bq = (const float*)d_in[4];
    const float* bk = (const float*)d_in[5];
    const float* bv = (const float*)d_in[6];
    float* out = (float*)d_out;

    const size_t N = (size_t)BB * HH * SS * DH;
    __hip_bfloat16* q_ws  = (__hip_bfloat16*)d_ws;
    __hip_bfloat16* k_ws  = q_ws + N;
    __hip_bfloat16* v_ws  = k_ws + N;   // vfrag layout
    __hip_bfloat16* wfrag = v_ws + N;   // 196608 bf16 = 384KB

    w_pack_kernel<<<dim3(12), dim3(256), 0, stream>>>(Wq, Wk, Wv, wfrag);
    qkv_proj_kernel<<<dim3(BB * HH * (SS / 128)), dim3(256), 0, stream>>>(
        x, wfrag, bq, bk, bv, q_ws, k_ws, v_ws);
    attn_kernel<<<dim3(BB * HH * (SS / 64 / 2)), dim3(512), 0, stream>>>(
        q_ws, k_ws, v_ws, out);
}

// Round 27
// 48.422 us; speedup vs baseline: 1.0908x; 1.0908x over previous
//
#include <hip/hip_runtime.h>
#include <hip/hip_bf16.h>

constexpr int BB = 4;
constexpr int SS = 1024;
constexpr int HH = 16;
constexpr int DH = 64;
constexpr int DM = 1024;

using f32x16 = __attribute__((ext_vector_type(16))) float;
using s16x8  = __attribute__((ext_vector_type(8))) short;

__device__ __forceinline__ f32x16 mfma32(s16x8 a, s16x8 b, f32x16 c) {
    return __builtin_amdgcn_mfma_f32_32x32x16_bf16(a, b, c, 0, 0, 0);
}

__device__ __forceinline__ unsigned short bf16bits(float x) {
    union { __hip_bfloat16 h; unsigned short s; } cv;
    cv.h = __float2bfloat16(x);
    return cv.s;
}
__device__ __forceinline__ unsigned pk_bf16(float lo, float hi) {
    return (unsigned)bf16bits(lo) | ((unsigned)bf16bits(hi) << 16);
}

__device__ __forceinline__ float fast_exp2(float x) {
#if __has_builtin(__builtin_amdgcn_exp2f)
    return __builtin_amdgcn_exp2f(x);
#else
    return __expf(x * 0.6931471805599453f);
#endif
}

// pi permutation within a 32-key group (involution): swap 4-7<->8-11, 20-23<->24-27.
__device__ __forceinline__ int kperm(int g) {
    const int m = g & 12;
    return (m == 4 || m == 8) ? (g ^ 12) : g;
}

// ---------------- W pre-pack: fp32 -> bf16 B-fragments, ONCE ----------------
// wfrag[h][m][s][hi][e]x8 : elem j = W_m[h][e][s*16+hi*8+j]
__global__ __launch_bounds__(256) void w_pack_kernel(
    const float* __restrict__ Wq, const float* __restrict__ Wk, const float* __restrict__ Wv,
    __hip_bfloat16* __restrict__ wfrag)
{
    const int gid = blockIdx.x * 256 + threadIdx.x;   // 0..3071 = h*192 + m*64 + e
    const int e = gid & 63;
    const int m = (gid >> 6) % 3;
    const int h = gid / 192;
    const float* Wm = (m == 0) ? Wq : (m == 1) ? Wk : Wv;
    const float* src = Wm + (size_t)(h * DH + e) * DH;
    s16x8* dst = reinterpret_cast<s16x8*>(wfrag);
    #pragma unroll
    for (int s = 0; s < 4; ++s) {
        #pragma unroll
        for (int hi = 0; hi < 2; ++hi) {
            const float* p = src + s * 16 + hi * 8;
            float4 a  = reinterpret_cast<const float4*>(p)[0];
            float4 b4 = reinterpret_cast<const float4*>(p)[1];
            union { unsigned u[4]; s16x8 v; } f;
            f.u[0] = pk_bf16(a.x, a.y);   f.u[1] = pk_bf16(a.z, a.w);
            f.u[2] = pk_bf16(b4.x, b4.y); f.u[3] = pk_bf16(b4.z, b4.w);
            dst[(((h * 3 + m) * 4 + s) * 2 + hi) * 64 + e] = f.v;
        }
    }
}

// ---------------- QKV projection (MFMA, pre-packed W fragments) ----------------
__global__ __launch_bounds__(256) void qkv_proj_kernel(
    const float* __restrict__ x,
    const __hip_bfloat16* __restrict__ wfrag,
    const float* __restrict__ bq, const float* __restrict__ bk, const float* __restrict__ bv,
    __hip_bfloat16* __restrict__ q_ws, __hip_bfloat16* __restrict__ k_ws,
    __hip_bfloat16* __restrict__ v_ws)
{
    const int bid  = blockIdx.x;
    const int tile = bid & 7;
    const int pair = bid >> 3;
    const int b = pair >> 4, h = pair & 15;
    const int t = threadIdx.x;
    const int w = t >> 6, l = t & 63;
    const int lq = l & 31, hi = l >> 5;
    const int s0 = tile * 128;

    __shared__ __align__(16) char Xs[16384];   // X stage [128 s][128B], then Q out
    __shared__ __align__(16) char Kt[16384];   // K out  [128 s][128B]
    __shared__ __align__(16) char Vt[16384];   // V out transposed [64 e][256B]

    {
        const float* xb = x + (size_t)(b * SS + s0) * DM + h * DH;
        #pragma unroll
        for (int i = 0; i < 8; ++i) {
            const int c  = t + 256 * i;
            const int r  = c >> 4, cw = c & 15;
            float4 v4 = *reinterpret_cast<const float4*>(xb + (size_t)r * DM + cw * 4);
            uint2 p;
            p.x = pk_bf16(v4.x, v4.y);
            p.y = pk_bf16(v4.z, v4.w);
            *reinterpret_cast<uint2*>(Xs + r * 128 + ((cw * 8) ^ ((r & 7) << 4))) = p;
        }
    }
    __syncthreads();

    const int arow = w * 32 + lq;
    const int asw  = (arow & 7) << 4;
    s16x8 af[4];
    #pragma unroll
    for (int s = 0; s < 4; ++s)
        af[s] = *reinterpret_cast<const s16x8*>(Xs + arow * 128 + ((s * 32 + hi * 16) ^ asw));
    __syncthreads();   // Xs now free for reuse as Q-out tile

    const s16x8* wfp = reinterpret_cast<const s16x8*>(wfrag);

    #pragma unroll
    for (int m = 0; m < 3; ++m) {
        const float* bm = (m == 0) ? bq : (m == 1) ? bk : bv;

        f32x16 a0, a1;
        #pragma unroll
        for (int r = 0; r < 16; ++r) { a0[r] = 0.0f; a1[r] = 0.0f; }

        #pragma unroll
        for (int s = 0; s < 4; ++s) {
            const int wb = (((h * 3 + m) * 4 + s) * 2 + hi) * 64;
            s16x8 bf0 = wfp[wb + lq];        // B-frag col e = lq
            s16x8 bf1 = wfp[wb + 32 + lq];   // B-frag col e = 32+lq
            a0 = mfma32(af[s], bf0, a0);
            a1 = mfma32(af[s], bf1, a1);
        }

        const float bias0 = bm[h * DH + lq];
        const float bias1 = bm[h * DH + 32 + lq];

        if (m < 2) {
            char* T = (m == 0) ? Xs : Kt;
            #pragma unroll
            for (int r = 0; r < 16; ++r) {
                const int row = w * 32 + (r & 3) + 8 * (r >> 2) + 4 * hi;
                const int sw  = (row & 7) << 4;
                *reinterpret_cast<unsigned short*>(T + row * 128 + ((lq * 2) ^ sw)) =
                    bf16bits(a0[r] + bias0);
                *reinterpret_cast<unsigned short*>(T + row * 128 + (((32 + lq) * 2) ^ sw)) =
                    bf16bits(a1[r] + bias1);
            }
        } else {
            #pragma unroll
            for (int g = 0; g < 4; ++g) {
                const int off = w * 64 + g * 16 + hi * 8;
                uint2 p0, p1;
                p0.x = pk_bf16(a0[4*g+0] + bias0, a0[4*g+1] + bias0);
                p0.y = pk_bf16(a0[4*g+2] + bias0, a0[4*g+3] + bias0);
                p1.x = pk_bf16(a1[4*g+0] + bias1, a1[4*g+1] + bias1);
                p1.y = pk_bf16(a1[4*g+2] + bias1, a1[4*g+3] + bias1);
                *reinterpret_cast<uint2*>(Vt + lq * 256 + (off ^ ((lq & 7) << 4))) = p0;
                *reinterpret_cast<uint2*>(Vt + (32 + lq) * 256 + (off ^ (((32 + lq) & 7) << 4))) = p1;
            }
        }
    }
    __syncthreads();

    #pragma unroll
    for (int i = 0; i < 4; ++i) {
        const int c   = t + 256 * i;
        const int row = c >> 3, cc = c & 7;
        const int off = row * 128 + ((cc * 16) ^ ((row & 7) << 4));
        s16x8 qv = *reinterpret_cast<const s16x8*>(Xs + off);
        *reinterpret_cast<s16x8*>(q_ws + ((size_t)pair * SS + s0 + row) * DH + cc * 8) = qv;
        s16x8 kv = *reinterpret_cast<const s16x8*>(Kt + off);
        *reinterpret_cast<s16x8*>(k_ws + ((size_t)pair * SS + s0 + row) * DH + cc * 8) = kv;
    }
    #pragma unroll
    for (int i = 0; i < 4; ++i) {
        const int c   = t + 256 * i;
        const int row = c >> 4, cc = c & 15;
        s16x8 vv = *reinterpret_cast<const s16x8*>(
            Vt + row * 256 + ((cc * 16) ^ ((row & 7) << 4)));
        *reinterpret_cast<s16x8*>(v_ws + ((size_t)pair * DH + row) * SS + s0 + cc * 8) = vv;
    }
}

// ---------------- Flash attention: round-15/23 structure (empirical best) ----------------
// grid 512; block 512 = 8 waves = 4 q-groups x 2 KV-parities; single 32KB K/V buffer.
// Static-max softmax; pi-permuted K store -> P->A repack pure in-lane; max-free merge.
__global__ __launch_bounds__(512, 4) void attn_kernel(
    const __hip_bfloat16* __restrict__ q_ws,
    const __hip_bfloat16* __restrict__ k_ws,
    const __hip_bfloat16* __restrict__ v_ws,
    float* __restrict__ out)
{
    const int bid  = blockIdx.x;
    const int lbid = (bid & 7) * 64 + (bid >> 3);   // XCD-aware swizzle (512 % 8 == 0)
    const int qt   = lbid & 7;
    const int pair = lbid >> 3;
    const int b = pair >> 4, h = pair & 15;
    const int t = threadIdx.x;
    const int w = t >> 6, l = t & 63;
    const int lq = l & 31, hi = l >> 5;
    const int qg = w & 3, p = w >> 2;

    __shared__ __align__(16) char smem[33792];

    const __hip_bfloat16* qp =
        q_ws + ((size_t)pair * SS + qt * 128 + qg * 32 + lq) * DH + hi * 8;
    s16x8 qf[4];
    #pragma unroll
    for (int s5 = 0; s5 < 4; ++s5)
        qf[s5] = *reinterpret_cast<const s16x8*>(qp + s5 * 16);

    const int u0 = t, u1 = t + 512;
    const __hip_bfloat16* kb = k_ws + (size_t)pair * SS * DH;
    const __hip_bfloat16* vb = v_ws + (size_t)pair * DH * SS;

    const int r0g = (u0 >> 3) & 31, r0m = r0g & 12;
    const int pr0 = (u0 >> 3 & ~31) | ((r0m == 4 || r0m == 8) ? (r0g ^ 12) : r0g);
    const int kOff0 = pr0 * 128 + (((u0 & 7) ^ (pr0 & 7)) << 4);
    const int r1g = (u1 >> 3) & 31, r1m = r1g & 12;
    const int pr1 = (u1 >> 3 & ~31) | ((r1m == 4 || r1m == 8) ? (r1g ^ 12) : r1g);
    const int kOff1 = pr1 * 128 + (((u1 & 7) ^ (pr1 & 7)) << 4);

    const int vOff0 = (u0 >> 4) * 256 + (((u0 & 15) ^ ((u0 >> 4) & 15)) << 4);
    const int vOff1 = (u1 >> 4) * 256 + (((u1 & 15) ^ ((u1 >> 4) & 15)) << 4);
    const size_t vs0 = (size_t)(u0 >> 4) * SS + (u0 & 15) * 8;
    const size_t vs1 = (size_t)(u1 >> 4) * SS + (u1 & 15) * 8;

    // prologue: super-tile 0 -> buf
    {
        s16x8 k0 = *reinterpret_cast<const s16x8*>(kb + u0 * 8);
        s16x8 k1 = *reinterpret_cast<const s16x8*>(kb + u1 * 8);
        s16x8 v0 = *reinterpret_cast<const s16x8*>(vb + vs0);
        s16x8 v1 = *reinterpret_cast<const s16x8*>(vb + vs1);
        *reinterpret_cast<s16x8*>(smem + kOff0) = k0;
        *reinterpret_cast<s16x8*>(smem + kOff1) = k1;
        *reinterpret_cast<s16x8*>(smem + 16384 + vOff0) = v0;
        *reinterpret_cast<s16x8*>(smem + 16384 + vOff1) = v1;
    }
    __syncthreads();

    f32x16 o0, o1, lacc;
    #pragma unroll
    for (int r = 0; r < 16; ++r) { o0[r] = 0.0f; o1[r] = 0.0f; lacc[r] = 0.0f; }
    const float cml = 0.18033688011112042f;  // log2(e)/8 : folds 1/sqrt(64) + exp2 domain

    const int kbase0 = (p * 64 + lq) * 128;
    const int kbase1 = kbase0 + 32 * 128;
    const int swzK = (lq & 7) << 4;
    const int swzV = (lq & 15) << 4;
    const int vrow0 = lq * 256, vrow1 = (32 + lq) * 256;

    s16x8 kr0, kr1, vr0, vr1;
    for (int st = 0; st < 8; ++st) {
        if (st < 7) {                              // T14: issue next super-tile loads first
            kr0 = *reinterpret_cast<const s16x8*>(kb + (st + 1) * 8192 + u0 * 8);
            kr1 = *reinterpret_cast<const s16x8*>(kb + (st + 1) * 8192 + u1 * 8);
            vr0 = *reinterpret_cast<const s16x8*>(vb + vs0 + (st + 1) * 128);
            vr1 = *reinterpret_cast<const s16x8*>(vb + vs1 + (st + 1) * 128);
        }
        const char* Kp = smem;
        const char* Vp = smem + 16384;

        // QK^T (swapped): lane = query lq; regs = 32 pi-permuted keys of the parity half
        f32x16 sc0, sc1;
        #pragma unroll
        for (int r = 0; r < 16; ++r) { sc0[r] = 0.0f; sc1[r] = 0.0f; }
        #pragma unroll
        for (int s5 = 0; s5 < 4; ++s5) {
            const int co = (2 * s5 + hi) << 4;
            s16x8 ka = *reinterpret_cast<const s16x8*>(Kp + kbase0 + (co ^ swzK));
            sc0 = mfma32(ka, qf[s5], sc0);
        }
        #pragma unroll
        for (int s5 = 0; s5 < 4; ++s5) {
            const int co = (2 * s5 + hi) << 4;
            s16x8 ka = *reinterpret_cast<const s16x8*>(Kp + kbase1 + (co ^ swzK));
            sc1 = mfma32(ka, qf[s5], sc1);
        }

        // static-max softmax: P = exp2(s*cml); per-reg sum accumulation
        #pragma unroll
        for (int r = 0; r < 16; ++r) {
            sc0[r] = fast_exp2(sc0[r] * cml);
            sc1[r] = fast_exp2(sc1[r] * cml);
            lacc[r] += sc0[r] + sc1[r];
        }

        // P -> A-frag: PURE in-lane packing (pi made each lane self-sufficient) + PV
        #pragma unroll
        for (int s5 = 0; s5 < 4; ++s5) {
            const int base = (s5 & 1) * 8;
            union { unsigned u[4]; s16x8 v; } afr;
            if (s5 < 2) {
                afr.u[0] = pk_bf16(sc0[base + 0], sc0[base + 1]);
                afr.u[1] = pk_bf16(sc0[base + 2], sc0[base + 3]);
                afr.u[2] = pk_bf16(sc0[base + 4], sc0[base + 5]);
                afr.u[3] = pk_bf16(sc0[base + 6], sc0[base + 7]);
            } else {
                afr.u[0] = pk_bf16(sc1[base + 0], sc1[base + 1]);
                afr.u[1] = pk_bf16(sc1[base + 2], sc1[base + 3]);
                afr.u[2] = pk_bf16(sc1[base + 4], sc1[base + 5]);
                afr.u[3] = pk_bf16(sc1[base + 6], sc1[base + 7]);
            }
            const int co = (2 * s5 + hi) << 4;
            s16x8 vb0 = *reinterpret_cast<const s16x8*>(Vp + vrow0 + ((p * 128 + co) ^ swzV));
            o0 = mfma32(afr.v, vb0, o0);
            s16x8 vb1 = *reinterpret_cast<const s16x8*>(Vp + vrow1 + ((p * 128 + co) ^ swzV));
            o1 = mfma32(afr.v, vb1, o1);
        }

        __syncthreads();                           // all waves done reading buf
        if (st < 7) {
            *reinterpret_cast<s16x8*>(smem + kOff0) = kr0;
            *reinterpret_cast<s16x8*>(smem + kOff1) = kr1;
            *reinterpret_cast<s16x8*>(smem + 16384 + vOff0) = vr0;
            *reinterpret_cast<s16x8*>(smem + 16384 + vOff1) = vr1;
            __syncthreads();                       // buf ready
        }
    }

    // ONE final reduction: tree over 16 regs + cross-half shfl -> lsum (per query lq)
    float ts[16];
    #pragma unroll
    for (int r = 0; r < 16; ++r) ts[r] = lacc[r];
    #pragma unroll
    for (int s = 8; s >= 1; s >>= 1)
        #pragma unroll
        for (int r = 0; r < 8; ++r)
            if (r < s) ts[r] += ts[r + s];
    const float lsum = ts[0] + __shfl_xor(ts[0], 32);

    // max-free split-K merge: (qg, p=0) <- (qg, p=1)
    float* Obuf = reinterpret_cast<float*>(smem + qg * 8192);          // [32 q][64 d] f32
    float* mlb  = reinterpret_cast<float*>(smem + 32768 + qg * 256);   // l[32]
    if (p == 1) {
        #pragma unroll
        for (int r = 0; r < 16; ++r) {
            const int qr = (r & 3) + 8 * (r >> 2) + 4 * hi;
            Obuf[qr * 64 + lq]      = o0[r];
            Obuf[qr * 64 + 32 + lq] = o1[r];
        }
        mlb[lq] = lsum;
    }
    __syncthreads();
    if (p == 0) {
        const float inv = 1.0f / (lsum + mlb[lq]);   // per query lq
        #pragma unroll
        for (int r = 0; r < 16; ++r) {
            const int qr = (r & 3) + 8 * (r >> 2) + 4 * hi;
            const float invr = __shfl(inv, qr);      // remap to query qr
            float* op = out + ((size_t)b * SS + qt * 128 + qg * 32 + qr) * DM + h * DH + lq;
            op[0]  = (o0[r] + Obuf[qr * 64 + lq])      * invr;
            op[32] = (o1[r] + Obuf[qr * 64 + 32 + lq]) * invr;
        }
    }
}

extern "C" void kernel_launch(void* const* d_in, const int* in_sizes, int n_in,
                              void* d_out, int out_size, void* d_ws, size_t ws_size,
                              hipStream_t stream) {
    const float* x  = (const float*)d_in[0];
    const float* Wq = (const float*)d_in[1];
    const float* Wk = (const float*)d_in[2];
    const float* Wv = (const float*)d_in[3];
    const float* bq = (const float*)d_in[4];
    const float* bk = (const float*)d_in[5];
    const float* bv = (const float*)d_in[6];
    float* out = (float*)d_out;

    const size_t N = (size_t)BB * HH * SS * DH;
    __hip_bfloat16* q_ws  = (__hip_bfloat16*)d_ws;
    __hip_bfloat16* k_ws  = q_ws + N;
    __hip_bfloat16* v_ws  = k_ws + N;
    __hip_bfloat16* wfrag = v_ws + N;   // 196608 bf16 = 384KB

    w_pack_kernel<<<dim3(12), dim3(256), 0, stream>>>(Wq, Wk, Wv, wfrag);
    qkv_proj_kernel<<<dim3(BB * HH * (SS / 128)), dim3(256), 0, stream>>>(
        x, wfrag, bq, bk, bv, q_ws, k_ws, v_ws);
    attn_kernel<<<dim3(BB * HH * (SS / 64 / 2)), dim3(512), 0, stream>>>(
        q_ws, k_ws, v_ws, out);
}

// Round 28
// 47.994 us; speedup vs baseline: 1.1005x; 1.0089x over previous
//
#include <hip/hip_runtime.h>
#include <hip/hip_bf16.h>

constexpr int BB = 4;
constexpr int SS = 1024;
constexpr int HH = 16;
constexpr int DH = 64;
constexpr int DM = 1024;

using f32x16 = __attribute__((ext_vector_type(16))) float;
using s16x8  = __attribute__((ext_vector_type(8))) short;

__device__ __forceinline__ f32x16 mfma32(s16x8 a, s16x8 b, f32x16 c) {
    return __builtin_amdgcn_mfma_f32_32x32x16_bf16(a, b, c, 0, 0, 0);
}

__device__ __forceinline__ unsigned short bf16bits(float x) {
    union { __hip_bfloat16 h; unsigned short s; } cv;
    cv.h = __float2bfloat16(x);
    return cv.s;
}
__device__ __forceinline__ unsigned pk_bf16(float lo, float hi) {
    return (unsigned)bf16bits(lo) | ((unsigned)bf16bits(hi) << 16);
}

__device__ __forceinline__ float fast_exp2(float x) {
#if __has_builtin(__builtin_amdgcn_exp2f)
    return __builtin_amdgcn_exp2f(x);
#else
    return __expf(x * 0.6931471805599453f);
#endif
}

// pi permutation within a 32-key group (involution): swap 4-7<->8-11, 20-23<->24-27.
__device__ __forceinline__ int kperm(int g) {
    const int m = g & 12;
    return (m == 4 || m == 8) ? (g ^ 12) : g;
}

// ---------------- W pre-pack: fp32 -> bf16 B-fragments, ONCE ----------------
// wfrag[h][m][s][hi][e]x8 : elem j = W_m[h][e][s*16+hi*8+j]
__global__ __launch_bounds__(256) void w_pack_kernel(
    const float* __restrict__ Wq, const float* __restrict__ Wk, const float* __restrict__ Wv,
    __hip_bfloat16* __restrict__ wfrag)
{
    const int gid = blockIdx.x * 256 + threadIdx.x;   // 0..3071 = h*192 + m*64 + e
    const int e = gid & 63;
    const int m = (gid >> 6) % 3;
    const int h = gid / 192;
    const float* Wm = (m == 0) ? Wq : (m == 1) ? Wk : Wv;
    const float* src = Wm + (size_t)(h * DH + e) * DH;
    s16x8* dst = reinterpret_cast<s16x8*>(wfrag);
    #pragma unroll
    for (int s = 0; s < 4; ++s) {
        #pragma unroll
        for (int hi = 0; hi < 2; ++hi) {
            const float* p = src + s * 16 + hi * 8;
            float4 a  = reinterpret_cast<const float4*>(p)[0];
            float4 b4 = reinterpret_cast<const float4*>(p)[1];
            union { unsigned u[4]; s16x8 v; } f;
            f.u[0] = pk_bf16(a.x, a.y);   f.u[1] = pk_bf16(a.z, a.w);
            f.u[2] = pk_bf16(b4.x, b4.y); f.u[3] = pk_bf16(b4.z, b4.w);
            dst[(((h * 3 + m) * 4 + s) * 2 + hi) * 64 + e] = f.v;
        }
    }
}

// ---------------- QKV projection (MFMA, pre-packed W fragments) ----------------
__global__ __launch_bounds__(256) void qkv_proj_kernel(
    const float* __restrict__ x,
    const __hip_bfloat16* __restrict__ wfrag,
    const float* __restrict__ bq, const float* __restrict__ bk, const float* __restrict__ bv,
    __hip_bfloat16* __restrict__ q_ws, __hip_bfloat16* __restrict__ k_ws,
    __hip_bfloat16* __restrict__ v_ws)
{
    const int bid  = blockIdx.x;
    const int tile = bid & 7;
    const int pair = bid >> 3;
    const int b = pair >> 4, h = pair & 15;
    const int t = threadIdx.x;
    const int w = t >> 6, l = t & 63;
    const int lq = l & 31, hi = l >> 5;
    const int s0 = tile * 128;

    __shared__ __align__(16) char Xs[16384];   // X stage [128 s][128B], then Q out
    __shared__ __align__(16) char Kt[16384];   // K out  [128 s][128B]
    __shared__ __align__(16) char Vt[16384];   // V out transposed [64 e][256B]

    {
        const float* xb = x + (size_t)(b * SS + s0) * DM + h * DH;
        #pragma unroll
        for (int i = 0; i < 8; ++i) {
            const int c  = t + 256 * i;
            const int r  = c >> 4, cw = c & 15;
            float4 v4 = *reinterpret_cast<const float4*>(xb + (size_t)r * DM + cw * 4);
            uint2 p;
            p.x = pk_bf16(v4.x, v4.y);
            p.y = pk_bf16(v4.z, v4.w);
            *reinterpret_cast<uint2*>(Xs + r * 128 + ((cw * 8) ^ ((r & 7) << 4))) = p;
        }
    }
    __syncthreads();

    const int arow = w * 32 + lq;
    const int asw  = (arow & 7) << 4;
    s16x8 af[4];
    #pragma unroll
    for (int s = 0; s < 4; ++s)
        af[s] = *reinterpret_cast<const s16x8*>(Xs + arow * 128 + ((s * 32 + hi * 16) ^ asw));
    __syncthreads();   // Xs now free for reuse as Q-out tile

    const s16x8* wfp = reinterpret_cast<const s16x8*>(wfrag);

    #pragma unroll
    for (int m = 0; m < 3; ++m) {
        const float* bm = (m == 0) ? bq : (m == 1) ? bk : bv;

        f32x16 a0, a1;
        #pragma unroll
        for (int r = 0; r < 16; ++r) { a0[r] = 0.0f; a1[r] = 0.0f; }

        #pragma unroll
        for (int s = 0; s < 4; ++s) {
            const int wb = (((h * 3 + m) * 4 + s) * 2 + hi) * 64;
            s16x8 bf0 = wfp[wb + lq];        // B-frag col e = lq
            s16x8 bf1 = wfp[wb + 32 + lq];   // B-frag col e = 32+lq
            a0 = mfma32(af[s], bf0, a0);
            a1 = mfma32(af[s], bf1, a1);
        }

        const float bias0 = bm[h * DH + lq];
        const float bias1 = bm[h * DH + 32 + lq];

        if (m < 2) {
            char* T = (m == 0) ? Xs : Kt;
            #pragma unroll
            for (int r = 0; r < 16; ++r) {
                const int row = w * 32 + (r & 3) + 8 * (r >> 2) + 4 * hi;
                const int sw  = (row & 7) << 4;
                *reinterpret_cast<unsigned short*>(T + row * 128 + ((lq * 2) ^ sw)) =
                    bf16bits(a0[r] + bias0);
                *reinterpret_cast<unsigned short*>(T + row * 128 + (((32 + lq) * 2) ^ sw)) =
                    bf16bits(a1[r] + bias1);
            }
        } else {
            #pragma unroll
            for (int g = 0; g < 4; ++g) {
                const int off = w * 64 + g * 16 + hi * 8;
                uint2 p0, p1;
                p0.x = pk_bf16(a0[4*g+0] + bias0, a0[4*g+1] + bias0);
                p0.y = pk_bf16(a0[4*g+2] + bias0, a0[4*g+3] + bias0);
                p1.x = pk_bf16(a1[4*g+0] + bias1, a1[4*g+1] + bias1);
                p1.y = pk_bf16(a1[4*g+2] + bias1, a1[4*g+3] + bias1);
                *reinterpret_cast<uint2*>(Vt + lq * 256 + (off ^ ((lq & 7) << 4))) = p0;
                *reinterpret_cast<uint2*>(Vt + (32 + lq) * 256 + (off ^ (((32 + lq) & 7) << 4))) = p1;
            }
        }
    }
    __syncthreads();

    #pragma unroll
    for (int i = 0; i < 4; ++i) {
        const int c   = t + 256 * i;
        const int row = c >> 3, cc = c & 7;
        const int off = row * 128 + ((cc * 16) ^ ((row & 7) << 4));
        s16x8 qv = *reinterpret_cast<const s16x8*>(Xs + off);
        *reinterpret_cast<s16x8*>(q_ws + ((size_t)pair * SS + s0 + row) * DH + cc * 8) = qv;
        s16x8 kv = *reinterpret_cast<const s16x8*>(Kt + off);
        *reinterpret_cast<s16x8*>(k_ws + ((size_t)pair * SS + s0 + row) * DH + cc * 8) = kv;
    }
    #pragma unroll
    for (int i = 0; i < 4; ++i) {
        const int c   = t + 256 * i;
        const int row = c >> 4, cc = c & 15;
        s16x8 vv = *reinterpret_cast<const s16x8*>(
            Vt + row * 256 + ((cc * 16) ^ ((row & 7) << 4)));
        *reinterpret_cast<s16x8*>(v_ws + ((size_t)pair * DH + row) * SS + s0 + cc * 8) = vv;
    }
}

// ---------------- Flash attention: round-15/23 structure (empirical best) ----------------
// grid 512; block 512 = 8 waves = 4 q-groups x 2 KV-parities; single 32KB K/V buffer.
// Static-max softmax; pi-permuted K store -> P->A repack pure in-lane; max-free merge.
__global__ __launch_bounds__(512, 4) void attn_kernel(
    const __hip_bfloat16* __restrict__ q_ws,
    const __hip_bfloat16* __restrict__ k_ws,
    const __hip_bfloat16* __restrict__ v_ws,
    float* __restrict__ out)
{
    const int bid  = blockIdx.x;
    const int lbid = (bid & 7) * 64 + (bid >> 3);   // XCD-aware swizzle (512 % 8 == 0)
    const int qt   = lbid & 7;
    const int pair = lbid >> 3;
    const int b = pair >> 4, h = pair & 15;
    const int t = threadIdx.x;
    const int w = t >> 6, l = t & 63;
    const int lq = l & 31, hi = l >> 5;
    const int qg = w & 3, p = w >> 2;

    __shared__ __align__(16) char smem[33792];

    const __hip_bfloat16* qp =
        q_ws + ((size_t)pair * SS + qt * 128 + qg * 32 + lq) * DH + hi * 8;
    s16x8 qf[4];
    #pragma unroll
    for (int s5 = 0; s5 < 4; ++s5)
        qf[s5] = *reinterpret_cast<const s16x8*>(qp + s5 * 16);

    const int u0 = t, u1 = t + 512;
    const __hip_bfloat16* kb = k_ws + (size_t)pair * SS * DH;
    const __hip_bfloat16* vb = v_ws + (size_t)pair * DH * SS;

    const int r0g = (u0 >> 3) & 31, r0m = r0g & 12;
    const int pr0 = (u0 >> 3 & ~31) | ((r0m == 4 || r0m == 8) ? (r0g ^ 12) : r0g);
    const int kOff0 = pr0 * 128 + (((u0 & 7) ^ (pr0 & 7)) << 4);
    const int r1g = (u1 >> 3) & 31, r1m = r1g & 12;
    const int pr1 = (u1 >> 3 & ~31) | ((r1m == 4 || r1m == 8) ? (r1g ^ 12) : r1g);
    const int kOff1 = pr1 * 128 + (((u1 & 7) ^ (pr1 & 7)) << 4);

    const int vOff0 = (u0 >> 4) * 256 + (((u0 & 15) ^ ((u0 >> 4) & 15)) << 4);
    const int vOff1 = (u1 >> 4) * 256 + (((u1 & 15) ^ ((u1 >> 4) & 15)) << 4);
    const size_t vs0 = (size_t)(u0 >> 4) * SS + (u0 & 15) * 8;
    const size_t vs1 = (size_t)(u1 >> 4) * SS + (u1 & 15) * 8;

    // prologue: super-tile 0 -> buf
    {
        s16x8 k0 = *reinterpret_cast<const s16x8*>(kb + u0 * 8);
        s16x8 k1 = *reinterpret_cast<const s16x8*>(kb + u1 * 8);
        s16x8 v0 = *reinterpret_cast<const s16x8*>(vb + vs0);
        s16x8 v1 = *reinterpret_cast<const s16x8*>(vb + vs1);
        *reinterpret_cast<s16x8*>(smem + kOff0) = k0;
        *reinterpret_cast<s16x8*>(smem + kOff1) = k1;
        *reinterpret_cast<s16x8*>(smem + 16384 + vOff0) = v0;
        *reinterpret_cast<s16x8*>(smem + 16384 + vOff1) = v1;
    }
    __syncthreads();

    f32x16 o0, o1, lacc;
    #pragma unroll
    for (int r = 0; r < 16; ++r) { o0[r] = 0.0f; o1[r] = 0.0f; lacc[r] = 0.0f; }
    const float cml = 0.18033688011112042f;  // log2(e)/8 : folds 1/sqrt(64) + exp2 domain

    const int kbase0 = (p * 64 + lq) * 128;
    const int kbase1 = kbase0 + 32 * 128;
    const int swzK = (lq & 7) << 4;
    const int swzV = (lq & 15) << 4;
    const int vrow0 = lq * 256, vrow1 = (32 + lq) * 256;

    s16x8 kr0, kr1, vr0, vr1;
    for (int st = 0; st < 8; ++st) {
        if (st < 7) {                              // T14: issue next super-tile loads first
            kr0 = *reinterpret_cast<const s16x8*>(kb + (st + 1) * 8192 + u0 * 8);
            kr1 = *reinterpret_cast<const s16x8*>(kb + (st + 1) * 8192 + u1 * 8);
            vr0 = *reinterpret_cast<const s16x8*>(vb + vs0 + (st + 1) * 128);
            vr1 = *reinterpret_cast<const s16x8*>(vb + vs1 + (st + 1) * 128);
        }
        const char* Kp = smem;
        const char* Vp = smem + 16384;

        // QK^T (swapped): lane = query lq; regs = 32 pi-permuted keys of the parity half
        f32x16 sc0, sc1;
        #pragma unroll
        for (int r = 0; r < 16; ++r) { sc0[r] = 0.0f; sc1[r] = 0.0f; }
        #pragma unroll
        for (int s5 = 0; s5 < 4; ++s5) {
            const int co = (2 * s5 + hi) << 4;
            s16x8 ka = *reinterpret_cast<const s16x8*>(Kp + kbase0 + (co ^ swzK));
            sc0 = mfma32(ka, qf[s5], sc0);
        }
        #pragma unroll
        for (int s5 = 0; s5 < 4; ++s5) {
            const int co = (2 * s5 + hi) << 4;
            s16x8 ka = *reinterpret_cast<const s16x8*>(Kp + kbase1 + (co ^ swzK));
            sc1 = mfma32(ka, qf[s5], sc1);
        }

        // static-max softmax: P = exp2(s*cml); per-reg sum accumulation
        #pragma unroll
        for (int r = 0; r < 16; ++r) {
            sc0[r] = fast_exp2(sc0[r] * cml);
            sc1[r] = fast_exp2(sc1[r] * cml);
            lacc[r] += sc0[r] + sc1[r];
        }

        // P -> A-frag: PURE in-lane packing (pi made each lane self-sufficient) + PV
        #pragma unroll
        for (int s5 = 0; s5 < 4; ++s5) {
            const int base = (s5 & 1) * 8;
            union { unsigned u[4]; s16x8 v; } afr;
            if (s5 < 2) {
                afr.u[0] = pk_bf16(sc0[base + 0], sc0[base + 1]);
                afr.u[1] = pk_bf16(sc0[base + 2], sc0[base + 3]);
                afr.u[2] = pk_bf16(sc0[base + 4], sc0[base + 5]);
                afr.u[3] = pk_bf16(sc0[base + 6], sc0[base + 7]);
            } else {
                afr.u[0] = pk_bf16(sc1[base + 0], sc1[base + 1]);
                afr.u[1] = pk_bf16(sc1[base + 2], sc1[base + 3]);
                afr.u[2] = pk_bf16(sc1[base + 4], sc1[base + 5]);
                afr.u[3] = pk_bf16(sc1[base + 6], sc1[base + 7]);
            }
            const int co = (2 * s5 + hi) << 4;
            s16x8 vb0 = *reinterpret_cast<const s16x8*>(Vp + vrow0 + ((p * 128 + co) ^ swzV));
            o0 = mfma32(afr.v, vb0, o0);
            s16x8 vb1 = *reinterpret_cast<const s16x8*>(Vp + vrow1 + ((p * 128 + co) ^ swzV));
            o1 = mfma32(afr.v, vb1, o1);
        }

        __syncthreads();                           // all waves done reading buf
        if (st < 7) {
            *reinterpret_cast<s16x8*>(smem + kOff0) = kr0;
            *reinterpret_cast<s16x8*>(smem + kOff1) = kr1;
            *reinterpret_cast<s16x8*>(smem + 16384 + vOff0) = vr0;
            *reinterpret_cast<s16x8*>(smem + 16384 + vOff1) = vr1;
            __syncthreads();                       // buf ready
        }
    }

    // ONE final reduction: tree over 16 regs + cross-half shfl -> lsum (per query lq)
    float ts[16];
    #pragma unroll
    for (int r = 0; r < 16; ++r) ts[r] = lacc[r];
    #pragma unroll
    for (int s = 8; s >= 1; s >>= 1)
        #pragma unroll
        for (int r = 0; r < 8; ++r)
            if (r < s) ts[r] += ts[r + s];
    const float lsum = ts[0] + __shfl_xor(ts[0], 32);

    // max-free split-K merge: (qg, p=0) <- (qg, p=1)
    float* Obuf = reinterpret_cast<float*>(smem + qg * 8192);          // [32 q][64 d] f32
    float* mlb  = reinterpret_cast<float*>(smem + 32768 + qg * 256);   // l[32]
    if (p == 1) {
        #pragma unroll
        for (int r = 0; r < 16; ++r) {
            const int qr = (r & 3) + 8 * (r >> 2) + 4 * hi;
            Obuf[qr * 64 + lq]      = o0[r];
            Obuf[qr * 64 + 32 + lq] = o1[r];
        }
        mlb[lq] = lsum;
    }
    __syncthreads();
    if (p == 0) {
        const float inv = 1.0f / (lsum + mlb[lq]);   // per query lq
        #pragma unroll
        for (int r = 0; r < 16; ++r) {
            const int qr = (r & 3) + 8 * (r >> 2) + 4 * hi;
            const float invr = __shfl(inv, qr);      // remap to query qr
            float* op = out + ((size_t)b * SS + qt * 128 + qg * 32 + qr) * DM + h * DH + lq;
            op[0]  = (o0[r] + Obuf[qr * 64 + lq])      * invr;
            op[32] = (o1[r] + Obuf[qr * 64 + 32 + lq]) * invr;
        }
    }
}

extern "C" void kernel_launch(void* const* d_in, const int* in_sizes, int n_in,
                              void* d_out, int out_size, void* d_ws, size_t ws_size,
                              hipStream_t stream) {
    const float* x  = (const float*)d_in[0];
    const float* Wq = (const float*)d_in[1];
    const float* Wk = (const float*)d_in[2];
    const float* Wv = (const float*)d_in[3];
    const float* bq = (const float*)d_in[4];
    const float* bk = (const float*)d_in[5];
    const float* bv = (const float*)d_in[6];
    float* out = (float*)d_out;

    const size_t N = (size_t)BB * HH * SS * DH;
    __hip_bfloat16* q_ws  = (__hip_bfloat16*)d_ws;
    __hip_bfloat16* k_ws  = q_ws + N;
    __hip_bfloat16* v_ws  = k_ws + N;
    __hip_bfloat16* wfrag = v_ws + N;   // 196608 bf16 = 384KB

    w_pack_kernel<<<dim3(12), dim3(256), 0, stream>>>(Wq, Wk, Wv, wfrag);
    qkv_proj_kernel<<<dim3(BB * HH * (SS / 128)), dim3(256), 0, stream>>>(
        x, wfrag, bq, bk, bv, q_ws, k_ws, v_ws);
    attn_kernel<<<dim3(BB * HH * (SS / 64 / 2)), dim3(512), 0, stream>>>(
        q_ws, k_ws, v_ws, out);
}